// Round 1
// baseline (27375.589 us; speedup 1.0000x reference)
//
#include <hip/hip_runtime.h>

#define N_NODES   50000
#define N_EDGES   800000
#define N_REL     6
#define N_LAYERS  8
#define DD        256
#define NUM_GRAPHS 512

__device__ __forceinline__ void atomAddF(float* p, float v) { unsafeAtomicAdd(p, v); }

// ---------------- encoder: h = x @ enc_W + enc_b  (K=13) ----------------
__global__ __launch_bounds__(256) void enc_kernel(const float* __restrict__ x,
                                                  const float* __restrict__ W,
                                                  const float* __restrict__ b,
                                                  float* __restrict__ h) {
    int n = blockIdx.x;
    int d = threadIdx.x;
    float s = b[d];
#pragma unroll
    for (int k = 0; k < 13; ++k) s = fmaf(x[n * 13 + k], W[k * 256 + d], s);
    h[(size_t)n * 256 + d] = s;
}

// ---------------- tiled fp32 GEMM: C[MxN] = A[MxK] @ B[KxN] (+epilogue) ----
// block tile 128x64, 256 threads, thread tile 8x4, BK=16.
// MODE 0: C = AB        MODE 1: C = AB + bias + aux (aux same layout as C)
// MODE 2: C = relu(AB + bias)   MODE 3: C = AB + bias
template <int MODE>
__global__ __launch_bounds__(256) void gemm128x64(const float* __restrict__ A,
                                                  const float* __restrict__ B,
                                                  float* __restrict__ C,
                                                  const float* __restrict__ bias,
                                                  const float* __restrict__ aux,
                                                  int M, int N, int K) {
    __shared__ float As[16 * 132];  // [k][m], padded ld=132 (528B, 16B-aligned)
    __shared__ float Bs[16 * 68];   // [k][n], padded ld=68  (272B, 16B-aligned)

    const int t  = threadIdx.x;
    const int tx = t & 15;   // col group (x4)
    const int ty = t >> 4;   // row group (x8)
    const int m0 = blockIdx.x * 128;
    const int n0 = blockIdx.y * 64;

    const int arow = t >> 2;        // 0..63
    const int ak   = (t & 3) * 4;   // k offset within tile
    const int bk   = t >> 4;        // 0..15
    const int bc   = (t & 15) * 4;  // col offset

    float acc[8][4];
#pragma unroll
    for (int i = 0; i < 8; ++i)
#pragma unroll
        for (int j = 0; j < 4; ++j) acc[i][j] = 0.f;

    for (int k0 = 0; k0 < K; k0 += 16) {
        float4 a0 = {0.f, 0.f, 0.f, 0.f}, a1 = {0.f, 0.f, 0.f, 0.f};
        const int r0 = m0 + arow, r1 = r0 + 64;
        if (r0 < M) a0 = *reinterpret_cast<const float4*>(A + (size_t)r0 * K + k0 + ak);
        if (r1 < M) a1 = *reinterpret_cast<const float4*>(A + (size_t)r1 * K + k0 + ak);
        const float4 bb = *reinterpret_cast<const float4*>(B + (size_t)(k0 + bk) * N + n0 + bc);

        __syncthreads();
        As[(ak + 0) * 132 + arow] = a0.x;
        As[(ak + 1) * 132 + arow] = a0.y;
        As[(ak + 2) * 132 + arow] = a0.z;
        As[(ak + 3) * 132 + arow] = a0.w;
        As[(ak + 0) * 132 + arow + 64] = a1.x;
        As[(ak + 1) * 132 + arow + 64] = a1.y;
        As[(ak + 2) * 132 + arow + 64] = a1.z;
        As[(ak + 3) * 132 + arow + 64] = a1.w;
        *reinterpret_cast<float4*>(&Bs[bk * 68 + bc]) = bb;
        __syncthreads();

#pragma unroll
        for (int k = 0; k < 16; ++k) {
            const float4 fa0 = *reinterpret_cast<const float4*>(&As[k * 132 + ty * 8]);
            const float4 fa1 = *reinterpret_cast<const float4*>(&As[k * 132 + ty * 8 + 4]);
            const float4 fb  = *reinterpret_cast<const float4*>(&Bs[k * 68 + tx * 4]);
            const float av[8] = {fa0.x, fa0.y, fa0.z, fa0.w, fa1.x, fa1.y, fa1.z, fa1.w};
            const float bv[4] = {fb.x, fb.y, fb.z, fb.w};
#pragma unroll
            for (int i = 0; i < 8; ++i)
#pragma unroll
                for (int j = 0; j < 4; ++j) acc[i][j] = fmaf(av[i], bv[j], acc[i][j]);
        }
    }

    const int row = m0 + ty * 8;
    const int col = n0 + tx * 4;
    float4 bv = {0.f, 0.f, 0.f, 0.f};
    if (MODE != 0) bv = *reinterpret_cast<const float4*>(bias + col);
#pragma unroll
    for (int i = 0; i < 8; ++i) {
        const int m = row + i;
        if (m >= M) continue;
        float4 v = {acc[i][0], acc[i][1], acc[i][2], acc[i][3]};
        if (MODE == 1) {
            const float4 av = *reinterpret_cast<const float4*>(aux + (size_t)m * N + col);
            v.x += bv.x + av.x; v.y += bv.y + av.y; v.z += bv.z + av.z; v.w += bv.w + av.w;
        } else if (MODE == 2) {
            v.x = fmaxf(v.x + bv.x, 0.f); v.y = fmaxf(v.y + bv.y, 0.f);
            v.z = fmaxf(v.z + bv.z, 0.f); v.w = fmaxf(v.w + bv.w, 0.f);
        } else if (MODE == 3) {
            v.x += bv.x; v.y += bv.y; v.z += bv.z; v.w += bv.w;
        }
        *reinterpret_cast<float4*>(C + (size_t)m * N + col) = v;
    }
}

// ---------------- scatter: base[dst] += xw[src] for edges of relation r ----
// one wave (64 lanes) per edge; lane handles 4 consecutive floats.
__global__ __launch_bounds__(256) void scatter_kernel(const float* __restrict__ xw,
                                                      const int* __restrict__ src,
                                                      const int* __restrict__ dst,
                                                      const int* __restrict__ etype,
                                                      float* __restrict__ base, int rel) {
    const unsigned gid  = blockIdx.x * 256u + threadIdx.x;
    const unsigned e    = gid >> 6;
    const unsigned lane = gid & 63;
    if (e >= N_EDGES) return;
    if (etype[e] != rel) return;
    const int s = src[e];
    const int d = dst[e];
    const float4 v = reinterpret_cast<const float4*>(xw + (size_t)s * DD)[lane];
    float* p = base + (size_t)d * DD + lane * 4;
    atomAddF(p + 0, v.x);
    atomAddF(p + 1, v.y);
    atomAddF(p + 2, v.z);
    atomAddF(p + 3, v.w);
}

// ---------------- per-node PReLU + L2 normalize: h = norm(prelu(base)) -----
__global__ __launch_bounds__(256) void finalize_kernel(const float* __restrict__ base,
                                                       float* __restrict__ h,
                                                       const float* __restrict__ pa) {
    const int node = blockIdx.x * 4 + (threadIdx.x >> 6);
    const int lane = threadIdx.x & 63;
    if (node >= N_NODES) return;
    const float a = pa[0];
    float4 v = reinterpret_cast<const float4*>(base + (size_t)node * DD)[lane];
    v.x = v.x > 0.f ? v.x : a * v.x;
    v.y = v.y > 0.f ? v.y : a * v.y;
    v.z = v.z > 0.f ? v.z : a * v.z;
    v.w = v.w > 0.f ? v.w : a * v.w;
    float ss = fmaf(v.x, v.x, fmaf(v.y, v.y, fmaf(v.z, v.z, v.w * v.w)));
#pragma unroll
    for (int off = 32; off; off >>= 1) ss += __shfl_xor(ss, off, 64);
    const float inv = 1.0f / fmaxf(sqrtf(ss), 1e-12f);
    v.x *= inv; v.y *= inv; v.z *= inv; v.w *= inv;
    reinterpret_cast<float4*>(h + (size_t)node * DD)[lane] = v;
}

// ---------------- pooled[batch[n]] += g[n]  (batch sorted → run-accumulate) -
__global__ __launch_bounds__(64) void pool_kernel(const float* __restrict__ g,
                                                  const int* __restrict__ batch,
                                                  float* __restrict__ pooled) {
    const int c     = threadIdx.x;  // float4 lane 0..63
    const int start = blockIdx.x * 128;
    const int end   = min(start + 128, N_NODES);
    int cur = batch[start];
    float4 acc = {0.f, 0.f, 0.f, 0.f};
    for (int n = start; n < end; ++n) {
        const int bn = batch[n];
        if (bn != cur) {
            float* p = pooled + (size_t)cur * DD + c * 4;
            atomAddF(p + 0, acc.x); atomAddF(p + 1, acc.y);
            atomAddF(p + 2, acc.z); atomAddF(p + 3, acc.w);
            acc = {0.f, 0.f, 0.f, 0.f};
            cur = bn;
        }
        const float4 v = reinterpret_cast<const float4*>(g + (size_t)n * DD)[c];
        acc.x += v.x; acc.y += v.y; acc.z += v.z; acc.w += v.w;
    }
    float* p = pooled + (size_t)cur * DD + c * 4;
    atomAddF(p + 0, acc.x); atomAddF(p + 1, acc.y);
    atomAddF(p + 2, acc.z); atomAddF(p + 3, acc.w);
}

// ---------------- out = relu(z2 @ out_W + out_b), [512,512]@[512,1] --------
__global__ __launch_bounds__(64) void out_kernel(const float* __restrict__ z2,
                                                 const float* __restrict__ W,
                                                 const float* __restrict__ b,
                                                 float* __restrict__ out) {
    const int g = blockIdx.x;
    const int t = threadIdx.x;
    float s = 0.f;
#pragma unroll
    for (int j = 0; j < 8; ++j) s = fmaf(z2[(size_t)g * 512 + t + 64 * j], W[t + 64 * j], s);
#pragma unroll
    for (int off = 32; off; off >>= 1) s += __shfl_xor(s, off, 64);
    if (t == 0) {
        const float v = s + b[0];
        out[g] = v > 0.f ? v : 0.f;
    }
}

extern "C" void kernel_launch(void* const* d_in, const int* in_sizes, int n_in,
                              void* d_out, int out_size, void* d_ws, size_t ws_size,
                              hipStream_t stream) {
    const float* x       = (const float*)d_in[0];
    const int*   eidx    = (const int*)d_in[1];
    const int*   etype   = (const int*)d_in[2];
    const int*   batch   = (const int*)d_in[3];
    const float* enc_W   = (const float*)d_in[4];
    const float* enc_b   = (const float*)d_in[5];
    const float* prelu_a = (const float*)d_in[6];
    const float* rel_W   = (const float*)d_in[7];
    const float* root_W  = (const float*)d_in[8];
    const float* conv_b  = (const float*)d_in[9];
    const float* gp_W1   = (const float*)d_in[10];
    const float* gp_b1   = (const float*)d_in[11];
    const float* gp_W2   = (const float*)d_in[12];
    const float* gp_b2   = (const float*)d_in[13];
    const float* fc_W1   = (const float*)d_in[14];
    const float* fc_b1   = (const float*)d_in[15];
    const float* fc_W2   = (const float*)d_in[16];
    const float* fc_b2   = (const float*)d_in[17];
    const float* out_W   = (const float*)d_in[18];
    const float* out_b   = (const float*)d_in[19];
    float* out = (float*)d_out;

    float* ws     = (float*)d_ws;
    float* h      = ws;                              // 12.8M floats
    float* base   = h + (size_t)N_NODES * DD;        // 12.8M
    float* xw     = base + (size_t)N_NODES * DD;     // 12.8M
    float* pooled = xw + (size_t)N_NODES * DD;       // 131072
    float* z1     = pooled + (size_t)NUM_GRAPHS * DD;    // 524288
    float* z2     = z1 + (size_t)NUM_GRAPHS * 1024;      // 262144

    const int* src = eidx;
    const int* dst = eidx + N_EDGES;

    // encoder
    enc_kernel<<<N_NODES, 256, 0, stream>>>(x, enc_W, enc_b, h);

    const dim3 g50k((N_NODES + 127) / 128, DD / 64);
    const int scatter_blocks = (N_EDGES * 64) / 256;  // exact: 200000

    for (int L = 0; L < N_LAYERS; ++L) {
        // base = h @ root_W[L] + conv_b[L] + h   (root transform + bias + skip)
        gemm128x64<1><<<g50k, 256, 0, stream>>>(h, root_W + (size_t)L * DD * DD, base,
                                                conv_b + L * DD, h, N_NODES, DD, DD);
        for (int r = 0; r < N_REL; ++r) {
            gemm128x64<0><<<g50k, 256, 0, stream>>>(
                h, rel_W + ((size_t)L * N_REL + r) * DD * DD, xw, nullptr, nullptr,
                N_NODES, DD, DD);
            scatter_kernel<<<scatter_blocks, 256, 0, stream>>>(xw, src, dst, etype, base, r);
        }
        finalize_kernel<<<(N_NODES + 3) / 4, 256, 0, stream>>>(base, h, prelu_a);
    }

    // g1 = relu(h @ gp_W1 + gp_b1)   (into base)
    gemm128x64<2><<<g50k, 256, 0, stream>>>(h, gp_W1, base, gp_b1, nullptr, N_NODES, DD, DD);
    // g = g1 @ gp_W2 + gp_b2         (into xw)
    gemm128x64<3><<<g50k, 256, 0, stream>>>(base, gp_W2, xw, gp_b2, nullptr, N_NODES, DD, DD);

    hipMemsetAsync(pooled, 0, (size_t)NUM_GRAPHS * DD * sizeof(float), stream);
    pool_kernel<<<(N_NODES + 127) / 128, 64, 0, stream>>>(xw, batch, pooled);

    // z1 = relu(pooled @ fc_W1 + fc_b1)  [512,256]@[256,1024]
    gemm128x64<2><<<dim3(4, 16), 256, 0, stream>>>(pooled, fc_W1, z1, fc_b1, nullptr,
                                                   NUM_GRAPHS, 1024, DD);
    // z2 = relu(z1 @ fc_W2 + fc_b2)      [512,1024]@[1024,512]
    gemm128x64<2><<<dim3(4, 8), 256, 0, stream>>>(z1, fc_W2, z2, fc_b2, nullptr,
                                                  NUM_GRAPHS, 512, 1024);
    // out = relu(z2 @ out_W + out_b)
    out_kernel<<<NUM_GRAPHS, 64, 0, stream>>>(z2, out_W, out_b, out);
}

// Round 2
// 7553.651 us; speedup vs baseline: 3.6242x; 3.6242x over previous
//
#include <hip/hip_runtime.h>

#define N_NODES   50000
#define N_EDGES   800000
#define N_REL     6
#define N_LAYERS  8
#define DD        256
#define NUM_GRAPHS 512

#define NKEYS      (N_REL * N_NODES)   // 300000 buckets: key = rel*N_NODES + dst
#define SCAN_T     256
#define SCAN_E     8
#define SCAN_CHUNK (SCAN_T * SCAN_E)   // 2048
#define SCAN_NB    ((NKEYS + SCAN_CHUNK - 1) / SCAN_CHUNK)  // 147

__device__ __forceinline__ void atomAddF(float* p, float v) { unsafeAtomicAdd(p, v); }

// ---------------- encoder: h = x @ enc_W + enc_b  (K=13) ----------------
__global__ __launch_bounds__(256) void enc_kernel(const float* __restrict__ x,
                                                  const float* __restrict__ W,
                                                  const float* __restrict__ b,
                                                  float* __restrict__ h) {
    int n = blockIdx.x;
    int d = threadIdx.x;
    float s = b[d];
#pragma unroll
    for (int k = 0; k < 13; ++k) s = fmaf(x[n * 13 + k], W[k * 256 + d], s);
    h[(size_t)n * 256 + d] = s;
}

// ---------------- tiled fp32 GEMM: C[MxN] = A[MxK] @ B[KxN] (+epilogue) ----
// block tile 128x64, 256 threads, thread tile 8x4, BK=16.
// MODE 0: C = AB        MODE 1: C = AB + bias + aux (aux same layout as C)
// MODE 2: C = relu(AB + bias)   MODE 3: C = AB + bias
template <int MODE>
__global__ __launch_bounds__(256) void gemm128x64(const float* __restrict__ A,
                                                  const float* __restrict__ B,
                                                  float* __restrict__ C,
                                                  const float* __restrict__ bias,
                                                  const float* __restrict__ aux,
                                                  int M, int N, int K) {
    __shared__ float As[16 * 132];  // [k][m], padded ld=132
    __shared__ float Bs[16 * 68];   // [k][n], padded ld=68

    const int t  = threadIdx.x;
    const int tx = t & 15;
    const int ty = t >> 4;
    const int m0 = blockIdx.x * 128;
    const int n0 = blockIdx.y * 64;

    const int arow = t >> 2;
    const int ak   = (t & 3) * 4;
    const int bk   = t >> 4;
    const int bc   = (t & 15) * 4;

    float acc[8][4];
#pragma unroll
    for (int i = 0; i < 8; ++i)
#pragma unroll
        for (int j = 0; j < 4; ++j) acc[i][j] = 0.f;

    for (int k0 = 0; k0 < K; k0 += 16) {
        float4 a0 = {0.f, 0.f, 0.f, 0.f}, a1 = {0.f, 0.f, 0.f, 0.f};
        const int r0 = m0 + arow, r1 = r0 + 64;
        if (r0 < M) a0 = *reinterpret_cast<const float4*>(A + (size_t)r0 * K + k0 + ak);
        if (r1 < M) a1 = *reinterpret_cast<const float4*>(A + (size_t)r1 * K + k0 + ak);
        const float4 bb = *reinterpret_cast<const float4*>(B + (size_t)(k0 + bk) * N + n0 + bc);

        __syncthreads();
        As[(ak + 0) * 132 + arow] = a0.x;
        As[(ak + 1) * 132 + arow] = a0.y;
        As[(ak + 2) * 132 + arow] = a0.z;
        As[(ak + 3) * 132 + arow] = a0.w;
        As[(ak + 0) * 132 + arow + 64] = a1.x;
        As[(ak + 1) * 132 + arow + 64] = a1.y;
        As[(ak + 2) * 132 + arow + 64] = a1.z;
        As[(ak + 3) * 132 + arow + 64] = a1.w;
        *reinterpret_cast<float4*>(&Bs[bk * 68 + bc]) = bb;
        __syncthreads();

#pragma unroll
        for (int k = 0; k < 16; ++k) {
            const float4 fa0 = *reinterpret_cast<const float4*>(&As[k * 132 + ty * 8]);
            const float4 fa1 = *reinterpret_cast<const float4*>(&As[k * 132 + ty * 8 + 4]);
            const float4 fb  = *reinterpret_cast<const float4*>(&Bs[k * 68 + tx * 4]);
            const float av[8] = {fa0.x, fa0.y, fa0.z, fa0.w, fa1.x, fa1.y, fa1.z, fa1.w};
            const float bv[4] = {fb.x, fb.y, fb.z, fb.w};
#pragma unroll
            for (int i = 0; i < 8; ++i)
#pragma unroll
                for (int j = 0; j < 4; ++j) acc[i][j] = fmaf(av[i], bv[j], acc[i][j]);
        }
    }

    const int row = m0 + ty * 8;
    const int col = n0 + tx * 4;
    float4 bv = {0.f, 0.f, 0.f, 0.f};
    if (MODE != 0) bv = *reinterpret_cast<const float4*>(bias + col);
#pragma unroll
    for (int i = 0; i < 8; ++i) {
        const int m = row + i;
        if (m >= M) continue;
        float4 v = {acc[i][0], acc[i][1], acc[i][2], acc[i][3]};
        if (MODE == 1) {
            const float4 av = *reinterpret_cast<const float4*>(aux + (size_t)m * N + col);
            v.x += bv.x + av.x; v.y += bv.y + av.y; v.z += bv.z + av.z; v.w += bv.w + av.w;
        } else if (MODE == 2) {
            v.x = fmaxf(v.x + bv.x, 0.f); v.y = fmaxf(v.y + bv.y, 0.f);
            v.z = fmaxf(v.z + bv.z, 0.f); v.w = fmaxf(v.w + bv.w, 0.f);
        } else if (MODE == 3) {
            v.x += bv.x; v.y += bv.y; v.z += bv.z; v.w += bv.w;
        }
        *reinterpret_cast<float4*>(C + (size_t)m * N + col) = v;
    }
}

// ================= CSR build: counting sort by key = rel*N_NODES + dst ======
__global__ __launch_bounds__(256) void hist_kernel(const int* __restrict__ dst,
                                                   const int* __restrict__ etype,
                                                   int* __restrict__ cnt) {
    const int e = blockIdx.x * 256 + threadIdx.x;
    if (e >= N_EDGES) return;
    atomicAdd(&cnt[etype[e] * N_NODES + dst[e]], 1);
}

// per-chunk exclusive scan; bsum[b] = chunk total
__global__ __launch_bounds__(SCAN_T) void scan1_kernel(const int* __restrict__ cnt,
                                                       int* __restrict__ off,
                                                       int* __restrict__ bsum) {
    __shared__ int sh[SCAN_T];
    const int b = blockIdx.x, t = threadIdx.x;
    const int base = b * SCAN_CHUNK + t * SCAN_E;
    int pre[SCAN_E];
    int s = 0;
#pragma unroll
    for (int i = 0; i < SCAN_E; ++i) {
        const int x = (base + i < NKEYS) ? cnt[base + i] : 0;
        pre[i] = s;
        s += x;
    }
    sh[t] = s;
    __syncthreads();
    for (int d = 1; d < SCAN_T; d <<= 1) {
        const int x = (t >= d) ? sh[t - d] : 0;
        __syncthreads();
        sh[t] += x;
        __syncthreads();
    }
    const int toff = (t == 0) ? 0 : sh[t - 1];
#pragma unroll
    for (int i = 0; i < SCAN_E; ++i)
        if (base + i < NKEYS) off[base + i] = toff + pre[i];
    if (t == SCAN_T - 1) bsum[b] = sh[SCAN_T - 1];
}

// exclusive scan of bsum[n] in place (single block, n <= 2048)
__global__ __launch_bounds__(SCAN_T) void scan2_kernel(int* __restrict__ bsum, int n) {
    __shared__ int sh[SCAN_T];
    const int t = threadIdx.x;
    const int base = t * SCAN_E;
    int pre[SCAN_E];
    int s = 0;
#pragma unroll
    for (int i = 0; i < SCAN_E; ++i) {
        const int x = (base + i < n) ? bsum[base + i] : 0;
        pre[i] = s;
        s += x;
    }
    sh[t] = s;
    __syncthreads();
    for (int d = 1; d < SCAN_T; d <<= 1) {
        const int x = (t >= d) ? sh[t - d] : 0;
        __syncthreads();
        sh[t] += x;
        __syncthreads();
    }
    const int toff = (t == 0) ? 0 : sh[t - 1];
#pragma unroll
    for (int i = 0; i < SCAN_E; ++i)
        if (base + i < n) bsum[base + i] = toff + pre[i];
}

__global__ __launch_bounds__(SCAN_T) void scan3_kernel(int* __restrict__ off,
                                                       const int* __restrict__ bsum) {
    const int b = blockIdx.x, t = threadIdx.x;
    const int add = bsum[b];
    const int base = b * SCAN_CHUNK + t * SCAN_E;
#pragma unroll
    for (int i = 0; i < SCAN_E; ++i)
        if (base + i < NKEYS) off[base + i] += add;
    if (b == 0 && t == 0) off[NKEYS] = N_EDGES;
}

// place src of each edge into its (rel,dst) bucket slot
__global__ __launch_bounds__(256) void csr_fill_kernel(const int* __restrict__ src,
                                                       const int* __restrict__ dst,
                                                       const int* __restrict__ etype,
                                                       int* __restrict__ cursor,
                                                       int* __restrict__ sorted_src) {
    const int e = blockIdx.x * 256 + threadIdx.x;
    if (e >= N_EDGES) return;
    const int key = etype[e] * N_NODES + dst[e];
    const int pos = atomicAdd(&cursor[key], 1);
    sorted_src[pos] = src[e];
}

// ---------- atomic-free aggregation: base[n] += sum_{e in bucket(r,n)} xw[src_e]
// one wave per dst node; lane handles float4 at offset lane*4.
__global__ __launch_bounds__(256) void agg_kernel(const float* __restrict__ xw,
                                                  const int* __restrict__ off_rel,
                                                  const int* __restrict__ sorted_src,
                                                  float* __restrict__ base) {
    const int node = blockIdx.x * 4 + (threadIdx.x >> 6);
    const int lane = threadIdx.x & 63;
    if (node >= N_NODES) return;
    const int s0 = off_rel[node];
    const int s1 = off_rel[node + 1];
    if (s0 == s1) return;
    float4 acc = reinterpret_cast<const float4*>(base + (size_t)node * DD)[lane];
    for (int e = s0; e < s1; ++e) {
        const int s = sorted_src[e];
        const float4 v = reinterpret_cast<const float4*>(xw + (size_t)s * DD)[lane];
        acc.x += v.x; acc.y += v.y; acc.z += v.z; acc.w += v.w;
    }
    reinterpret_cast<float4*>(base + (size_t)node * DD)[lane] = acc;
}

// ---------------- per-node PReLU + L2 normalize: h = norm(prelu(base)) -----
__global__ __launch_bounds__(256) void finalize_kernel(const float* __restrict__ base,
                                                       float* __restrict__ h,
                                                       const float* __restrict__ pa) {
    const int node = blockIdx.x * 4 + (threadIdx.x >> 6);
    const int lane = threadIdx.x & 63;
    if (node >= N_NODES) return;
    const float a = pa[0];
    float4 v = reinterpret_cast<const float4*>(base + (size_t)node * DD)[lane];
    v.x = v.x > 0.f ? v.x : a * v.x;
    v.y = v.y > 0.f ? v.y : a * v.y;
    v.z = v.z > 0.f ? v.z : a * v.z;
    v.w = v.w > 0.f ? v.w : a * v.w;
    float ss = fmaf(v.x, v.x, fmaf(v.y, v.y, fmaf(v.z, v.z, v.w * v.w)));
#pragma unroll
    for (int off = 32; off; off >>= 1) ss += __shfl_xor(ss, off, 64);
    const float inv = 1.0f / fmaxf(sqrtf(ss), 1e-12f);
    v.x *= inv; v.y *= inv; v.z *= inv; v.w *= inv;
    reinterpret_cast<float4*>(h + (size_t)node * DD)[lane] = v;
}

// ---------------- pooled[batch[n]] += g[n]  (batch sorted → run-accumulate) -
__global__ __launch_bounds__(64) void pool_kernel(const float* __restrict__ g,
                                                  const int* __restrict__ batch,
                                                  float* __restrict__ pooled) {
    const int c     = threadIdx.x;
    const int start = blockIdx.x * 128;
    const int end   = min(start + 128, N_NODES);
    int cur = batch[start];
    float4 acc = {0.f, 0.f, 0.f, 0.f};
    for (int n = start; n < end; ++n) {
        const int bn = batch[n];
        if (bn != cur) {
            float* p = pooled + (size_t)cur * DD + c * 4;
            atomAddF(p + 0, acc.x); atomAddF(p + 1, acc.y);
            atomAddF(p + 2, acc.z); atomAddF(p + 3, acc.w);
            acc = {0.f, 0.f, 0.f, 0.f};
            cur = bn;
        }
        const float4 v = reinterpret_cast<const float4*>(g + (size_t)n * DD)[c];
        acc.x += v.x; acc.y += v.y; acc.z += v.z; acc.w += v.w;
    }
    float* p = pooled + (size_t)cur * DD + c * 4;
    atomAddF(p + 0, acc.x); atomAddF(p + 1, acc.y);
    atomAddF(p + 2, acc.z); atomAddF(p + 3, acc.w);
}

// ---------------- out = relu(z2 @ out_W + out_b), [512,512]@[512,1] --------
__global__ __launch_bounds__(64) void out_kernel(const float* __restrict__ z2,
                                                 const float* __restrict__ W,
                                                 const float* __restrict__ b,
                                                 float* __restrict__ out) {
    const int g = blockIdx.x;
    const int t = threadIdx.x;
    float s = 0.f;
#pragma unroll
    for (int j = 0; j < 8; ++j) s = fmaf(z2[(size_t)g * 512 + t + 64 * j], W[t + 64 * j], s);
#pragma unroll
    for (int off = 32; off; off >>= 1) s += __shfl_xor(s, off, 64);
    if (t == 0) {
        const float v = s + b[0];
        out[g] = v > 0.f ? v : 0.f;
    }
}

extern "C" void kernel_launch(void* const* d_in, const int* in_sizes, int n_in,
                              void* d_out, int out_size, void* d_ws, size_t ws_size,
                              hipStream_t stream) {
    const float* x       = (const float*)d_in[0];
    const int*   eidx    = (const int*)d_in[1];
    const int*   etype   = (const int*)d_in[2];
    const int*   batch   = (const int*)d_in[3];
    const float* enc_W   = (const float*)d_in[4];
    const float* enc_b   = (const float*)d_in[5];
    const float* prelu_a = (const float*)d_in[6];
    const float* rel_W   = (const float*)d_in[7];
    const float* root_W  = (const float*)d_in[8];
    const float* conv_b  = (const float*)d_in[9];
    const float* gp_W1   = (const float*)d_in[10];
    const float* gp_b1   = (const float*)d_in[11];
    const float* gp_W2   = (const float*)d_in[12];
    const float* gp_b2   = (const float*)d_in[13];
    const float* fc_W1   = (const float*)d_in[14];
    const float* fc_b1   = (const float*)d_in[15];
    const float* fc_W2   = (const float*)d_in[16];
    const float* fc_b2   = (const float*)d_in[17];
    const float* out_W   = (const float*)d_in[18];
    const float* out_b   = (const float*)d_in[19];
    float* out = (float*)d_out;

    float* ws     = (float*)d_ws;
    float* h      = ws;                                   // 12.8M floats
    float* base   = h + (size_t)N_NODES * DD;             // 12.8M
    float* xw     = base + (size_t)N_NODES * DD;          // 12.8M
    float* pooled = xw + (size_t)N_NODES * DD;            // 131072
    float* z1     = pooled + (size_t)NUM_GRAPHS * DD;     // 524288
    float* z2     = z1 + (size_t)NUM_GRAPHS * 1024;       // 262144
    int*   ioff   = (int*)(z2 + (size_t)NUM_GRAPHS * 512); // NKEYS+1
    int*   icur   = ioff + (NKEYS + 1);                    // NKEYS (hist, then cursor)
    int*   ibsum  = icur + NKEYS;                          // SCAN_NB (pad 256)
    int*   isrc   = ibsum + 256;                           // N_EDGES

    const int* src = eidx;
    const int* dst = eidx + N_EDGES;

    // ---- CSR build (per call; graph-capture-safe ops only) ----
    hipMemsetAsync(icur, 0, (size_t)NKEYS * sizeof(int), stream);
    const int eb = (N_EDGES + 255) / 256;
    hist_kernel<<<eb, 256, 0, stream>>>(dst, etype, icur);
    scan1_kernel<<<SCAN_NB, SCAN_T, 0, stream>>>(icur, ioff, ibsum);
    scan2_kernel<<<1, SCAN_T, 0, stream>>>(ibsum, SCAN_NB);
    scan3_kernel<<<SCAN_NB, SCAN_T, 0, stream>>>(ioff, ibsum);
    hipMemcpyAsync(icur, ioff, (size_t)NKEYS * sizeof(int), hipMemcpyDeviceToDevice, stream);
    csr_fill_kernel<<<eb, 256, 0, stream>>>(src, dst, etype, icur, isrc);

    // encoder
    enc_kernel<<<N_NODES, 256, 0, stream>>>(x, enc_W, enc_b, h);

    const dim3 g50k((N_NODES + 127) / 128, DD / 64);
    const int nodeb = (N_NODES + 3) / 4;

    for (int L = 0; L < N_LAYERS; ++L) {
        // base = h @ root_W[L] + conv_b[L] + h   (root transform + bias + skip)
        gemm128x64<1><<<g50k, 256, 0, stream>>>(h, root_W + (size_t)L * DD * DD, base,
                                                conv_b + L * DD, h, N_NODES, DD, DD);
        for (int r = 0; r < N_REL; ++r) {
            gemm128x64<0><<<g50k, 256, 0, stream>>>(
                h, rel_W + ((size_t)L * N_REL + r) * DD * DD, xw, nullptr, nullptr,
                N_NODES, DD, DD);
            agg_kernel<<<nodeb, 256, 0, stream>>>(xw, ioff + (size_t)r * N_NODES, isrc, base);
        }
        finalize_kernel<<<nodeb, 256, 0, stream>>>(base, h, prelu_a);
    }

    // g1 = relu(h @ gp_W1 + gp_b1)   (into base)
    gemm128x64<2><<<g50k, 256, 0, stream>>>(h, gp_W1, base, gp_b1, nullptr, N_NODES, DD, DD);
    // g = g1 @ gp_W2 + gp_b2         (into xw)
    gemm128x64<3><<<g50k, 256, 0, stream>>>(base, gp_W2, xw, gp_b2, nullptr, N_NODES, DD, DD);

    hipMemsetAsync(pooled, 0, (size_t)NUM_GRAPHS * DD * sizeof(float), stream);
    pool_kernel<<<(N_NODES + 127) / 128, 64, 0, stream>>>(xw, batch, pooled);

    // z1 = relu(pooled @ fc_W1 + fc_b1)  [512,256]@[256,1024]
    gemm128x64<2><<<dim3(4, 16), 256, 0, stream>>>(pooled, fc_W1, z1, fc_b1, nullptr,
                                                   NUM_GRAPHS, 1024, DD);
    // z2 = relu(z1 @ fc_W2 + fc_b2)      [512,1024]@[1024,512]
    gemm128x64<2><<<dim3(4, 8), 256, 0, stream>>>(z1, fc_W2, z2, fc_b2, nullptr,
                                                  NUM_GRAPHS, 512, 1024);
    // out = relu(z2 @ out_W + out_b)
    out_kernel<<<NUM_GRAPHS, 64, 0, stream>>>(z2, out_W, out_b, out);
}

// Round 3
// 5622.739 us; speedup vs baseline: 4.8687x; 1.3434x over previous
//
#include <hip/hip_runtime.h>

#define N_NODES   50000
#define N_EDGES   800000
#define N_REL     6
#define N_LAYERS  8
#define DD        256
#define NUM_GRAPHS 512

#define NKEYS      (N_REL * N_NODES)
#define SCAN_T     256
#define SCAN_E     8
#define SCAN_CHUNK (SCAN_T * SCAN_E)
#define SCAN_NB    ((NKEYS + SCAN_CHUNK - 1) / SCAN_CHUNK)

typedef _Float16 h4 __attribute__((ext_vector_type(4)));
typedef _Float16 h8 __attribute__((ext_vector_type(8)));
typedef float    f4 __attribute__((ext_vector_type(4)));

__device__ __forceinline__ void atomAddF(float* p, float v) { unsafeAtomicAdd(p, v); }

// ---------------- encoder: h = x @ enc_W + enc_b, write hi/lo fp16 planes ---
__global__ __launch_bounds__(256) void enc_kernel(const float* __restrict__ x,
                                                  const float* __restrict__ W,
                                                  const float* __restrict__ b,
                                                  _Float16* __restrict__ Hhi,
                                                  _Float16* __restrict__ Hlo) {
    int n = blockIdx.x;
    int d = threadIdx.x;
    float s = b[d];
#pragma unroll
    for (int k = 0; k < 13; ++k) s = fmaf(x[n * 13 + k], W[k * 256 + d], s);
    const _Float16 hi = (_Float16)s;
    Hhi[(size_t)n * DD + d] = hi;
    Hlo[(size_t)n * DD + d] = (_Float16)(s - (float)hi);
}

// ---------------- weight split+transpose: rel_W/root_W -> WT[L][n][1792] ----
__global__ __launch_bounds__(256) void wsplit_rel_kernel(const float* __restrict__ relW,
                                                         const float* __restrict__ rootW,
                                                         _Float16* __restrict__ wthi,
                                                         _Float16* __restrict__ wtlo) {
    const size_t id = (size_t)blockIdx.x * 256 + threadIdx.x;
    if (id >= (size_t)N_LAYERS * 7 * 256 * 256) return;
    const int k = (int)(id & 255);
    const int n = (int)((id >> 8) & 255);
    const int g = (int)((id >> 16) % 7);
    const int L = (int)((id >> 16) / 7);
    const float w = (g < 6)
        ? relW[(((size_t)L * 6 + g) * 256 + k) * 256 + n]
        : rootW[((size_t)L * 256 + k) * 256 + n];
    const _Float16 hi = (_Float16)w;
    const size_t o = ((size_t)L * 256 + n) * 1792 + (size_t)g * 256 + k;
    wthi[o] = hi;
    wtlo[o] = (_Float16)(w - (float)hi);
}

// generic 256x256 [k][n] -> split planes [n][k]
__global__ __launch_bounds__(256) void wsplit_tr_kernel(const float* __restrict__ W,
                                                        _Float16* __restrict__ whi,
                                                        _Float16* __restrict__ wlo) {
    const int id = blockIdx.x * 256 + threadIdx.x;  // 65536
    const int k = id & 255, n = id >> 8;
    const float w = W[(size_t)k * 256 + n];
    const _Float16 hi = (_Float16)w;
    whi[(size_t)n * 256 + k] = hi;
    wlo[(size_t)n * 256 + k] = (_Float16)(w - (float)hi);
}

// ---------------- MFMA GEMM: C[M x 256] = A @ B, fp16 hi/lo 3-term split ----
// A = [agg segments (K_agg) | h segment (K_tot-K_agg)], planes row-stride 256.
// B planes: [n][ldb] pre-transposed. Block 128x128, 4 waves of 64x64.
// MODE 0: Cf = acc + bias + (Hhi+Hlo)      (root GEMM: bias + skip)
// MODE 1: Cf += acc                        (K-chunk accumulate)
// MODE 2: relu(acc + bias) -> Ohi/Olo planes
// MODE 3: Cf = acc + bias
template <int MODE>
__global__ __launch_bounds__(256) void mfma_gemm(
    const _Float16* __restrict__ Ahi, const _Float16* __restrict__ Alo,
    const _Float16* __restrict__ Hhi, const _Float16* __restrict__ Hlo,
    const _Float16* __restrict__ Bhi, const _Float16* __restrict__ Blo,
    int ldb, int boff_agg, int boff_h, int K_agg, int K_tot,
    float* __restrict__ Cf, _Float16* __restrict__ Ohi, _Float16* __restrict__ Olo,
    const float* __restrict__ bias, int M) {
    const int tid  = threadIdx.x;
    const int lane = tid & 63;
    const int wave = tid >> 6;
    const int lm = lane & 15, lq = lane >> 4;
    const int m0w = blockIdx.x * 128 + (wave & 1) * 64;
    const int n0w = blockIdx.y * 128 + (wave >> 1) * 64;

    f4 acc[4][4];
#pragma unroll
    for (int i = 0; i < 4; ++i)
#pragma unroll
        for (int j = 0; j < 4; ++j) acc[i][j] = (f4){0.f, 0.f, 0.f, 0.f};

    for (int k0 = 0; k0 < K_tot; k0 += 32) {
        const _Float16 *pAh, *pAl;
        int acol, bcol;
        if (k0 < K_agg) {
            const size_t pb = (size_t)(k0 >> 8) * (size_t)M * DD;
            pAh = Ahi + pb; pAl = Alo + pb;
            acol = k0 & 255;
            bcol = boff_agg + k0;
        } else {
            pAh = Hhi; pAl = Hlo;
            acol = k0 - K_agg;
            bcol = boff_h + (k0 - K_agg);
        }
        h8 ah[4], al[4], bh[4], bl[4];
#pragma unroll
        for (int j = 0; j < 4; ++j) {
            const size_t bo = (size_t)(n0w + j * 16 + lm) * ldb + bcol + lq * 8;
            bh[j] = *(const h8*)(Bhi + bo);
            bl[j] = *(const h8*)(Blo + bo);
        }
#pragma unroll
        for (int i = 0; i < 4; ++i) {
            int row = m0w + i * 16 + lm;
            if (row >= M) row = M - 1;
            const size_t ao = (size_t)row * DD + acol + lq * 8;
            ah[i] = *(const h8*)(pAh + ao);
            al[i] = *(const h8*)(pAl + ao);
        }
#pragma unroll
        for (int i = 0; i < 4; ++i)
#pragma unroll
            for (int j = 0; j < 4; ++j) {
                acc[i][j] = __builtin_amdgcn_mfma_f32_16x16x32_f16(ah[i], bh[j], acc[i][j], 0, 0, 0);
                acc[i][j] = __builtin_amdgcn_mfma_f32_16x16x32_f16(ah[i], bl[j], acc[i][j], 0, 0, 0);
                acc[i][j] = __builtin_amdgcn_mfma_f32_16x16x32_f16(al[i], bh[j], acc[i][j], 0, 0, 0);
            }
    }

#pragma unroll
    for (int i = 0; i < 4; ++i) {
        const int rowb = m0w + i * 16 + lq * 4;
#pragma unroll
        for (int r = 0; r < 4; ++r) {
            const int row = rowb + r;
            if (row >= M) continue;
#pragma unroll
            for (int j = 0; j < 4; ++j) {
                const int col = n0w + j * 16 + lm;
                const size_t idx = (size_t)row * DD + col;
                float v = acc[i][j][r];
                if (MODE == 0) {
                    v += bias[col] + (float)Hhi[idx] + (float)Hlo[idx];
                    Cf[idx] = v;
                } else if (MODE == 1) {
                    Cf[idx] += v;
                } else if (MODE == 2) {
                    v = fmaxf(v + bias[col], 0.f);
                    const _Float16 hi = (_Float16)v;
                    Ohi[idx] = hi;
                    Olo[idx] = (_Float16)(v - (float)hi);
                } else {
                    Cf[idx] = v + bias[col];
                }
            }
        }
    }
}

// ================= CSR build: counting sort by key = rel*N_NODES + dst ======
__global__ __launch_bounds__(256) void hist_kernel(const int* __restrict__ dst,
                                                   const int* __restrict__ etype,
                                                   int* __restrict__ cnt) {
    const int e = blockIdx.x * 256 + threadIdx.x;
    if (e >= N_EDGES) return;
    atomicAdd(&cnt[etype[e] * N_NODES + dst[e]], 1);
}

__global__ __launch_bounds__(SCAN_T) void scan1_kernel(const int* __restrict__ cnt,
                                                       int* __restrict__ off,
                                                       int* __restrict__ bsum) {
    __shared__ int sh[SCAN_T];
    const int b = blockIdx.x, t = threadIdx.x;
    const int base = b * SCAN_CHUNK + t * SCAN_E;
    int pre[SCAN_E];
    int s = 0;
#pragma unroll
    for (int i = 0; i < SCAN_E; ++i) {
        const int x = (base + i < NKEYS) ? cnt[base + i] : 0;
        pre[i] = s;
        s += x;
    }
    sh[t] = s;
    __syncthreads();
    for (int d = 1; d < SCAN_T; d <<= 1) {
        const int x = (t >= d) ? sh[t - d] : 0;
        __syncthreads();
        sh[t] += x;
        __syncthreads();
    }
    const int toff = (t == 0) ? 0 : sh[t - 1];
#pragma unroll
    for (int i = 0; i < SCAN_E; ++i)
        if (base + i < NKEYS) off[base + i] = toff + pre[i];
    if (t == SCAN_T - 1) bsum[b] = sh[SCAN_T - 1];
}

__global__ __launch_bounds__(SCAN_T) void scan2_kernel(int* __restrict__ bsum, int n) {
    __shared__ int sh[SCAN_T];
    const int t = threadIdx.x;
    const int base = t * SCAN_E;
    int pre[SCAN_E];
    int s = 0;
#pragma unroll
    for (int i = 0; i < SCAN_E; ++i) {
        const int x = (base + i < n) ? bsum[base + i] : 0;
        pre[i] = s;
        s += x;
    }
    sh[t] = s;
    __syncthreads();
    for (int d = 1; d < SCAN_T; d <<= 1) {
        const int x = (t >= d) ? sh[t - d] : 0;
        __syncthreads();
        sh[t] += x;
        __syncthreads();
    }
    const int toff = (t == 0) ? 0 : sh[t - 1];
#pragma unroll
    for (int i = 0; i < SCAN_E; ++i)
        if (base + i < n) bsum[base + i] = toff + pre[i];
}

__global__ __launch_bounds__(SCAN_T) void scan3_kernel(int* __restrict__ off,
                                                       const int* __restrict__ bsum) {
    const int b = blockIdx.x, t = threadIdx.x;
    const int add = bsum[b];
    const int base = b * SCAN_CHUNK + t * SCAN_E;
#pragma unroll
    for (int i = 0; i < SCAN_E; ++i)
        if (base + i < NKEYS) off[base + i] += add;
    if (b == 0 && t == 0) off[NKEYS] = N_EDGES;
}

__global__ __launch_bounds__(256) void csr_fill_kernel(const int* __restrict__ src,
                                                       const int* __restrict__ dst,
                                                       const int* __restrict__ etype,
                                                       int* __restrict__ cursor,
                                                       int* __restrict__ sorted_src) {
    const int e = blockIdx.x * 256 + threadIdx.x;
    if (e >= N_EDGES) return;
    const int key = etype[e] * N_NODES + dst[e];
    const int pos = atomicAdd(&cursor[key], 1);
    sorted_src[pos] = src[e];
}

// ---------- aggregation of h (hi+lo planes) for 2 relations -> agg planes ---
__global__ __launch_bounds__(256) void agg2_kernel(const _Float16* __restrict__ Hhi,
                                                   const _Float16* __restrict__ Hlo,
                                                   const int* __restrict__ off,
                                                   const int* __restrict__ isrc,
                                                   _Float16* __restrict__ agghi,
                                                   _Float16* __restrict__ agglo, int rel0) {
    const int node = blockIdx.x * 4 + (threadIdx.x >> 6);
    const int lane = threadIdx.x & 63;
    if (node >= N_NODES) return;
#pragma unroll
    for (int rl = 0; rl < 2; ++rl) {
        const int r = rel0 + rl;
        const int s0 = off[r * N_NODES + node];
        const int s1 = off[r * N_NODES + node + 1];
        float a0 = 0.f, a1 = 0.f, a2 = 0.f, a3 = 0.f;
        for (int e = s0; e < s1; ++e) {
            const int s = isrc[e];
            const h4 vh = *(const h4*)(Hhi + (size_t)s * DD + lane * 4);
            const h4 vl = *(const h4*)(Hlo + (size_t)s * DD + lane * 4);
            a0 += (float)vh[0] + (float)vl[0];
            a1 += (float)vh[1] + (float)vl[1];
            a2 += (float)vh[2] + (float)vl[2];
            a3 += (float)vh[3] + (float)vl[3];
        }
        h4 oh, ol;
        oh[0] = (_Float16)a0; ol[0] = (_Float16)(a0 - (float)oh[0]);
        oh[1] = (_Float16)a1; ol[1] = (_Float16)(a1 - (float)oh[1]);
        oh[2] = (_Float16)a2; ol[2] = (_Float16)(a2 - (float)oh[2]);
        oh[3] = (_Float16)a3; ol[3] = (_Float16)(a3 - (float)oh[3]);
        const size_t o = ((size_t)rl * N_NODES + node) * DD + lane * 4;
        *(h4*)(agghi + o) = oh;
        *(h4*)(agglo + o) = ol;
    }
}

// ---------------- per-node PReLU + L2 normalize -> h hi/lo planes -----------
__global__ __launch_bounds__(256) void finalize_kernel(const float* __restrict__ base,
                                                       _Float16* __restrict__ Hhi,
                                                       _Float16* __restrict__ Hlo,
                                                       const float* __restrict__ pa) {
    const int node = blockIdx.x * 4 + (threadIdx.x >> 6);
    const int lane = threadIdx.x & 63;
    if (node >= N_NODES) return;
    const float a = pa[0];
    float4 v = reinterpret_cast<const float4*>(base + (size_t)node * DD)[lane];
    v.x = v.x > 0.f ? v.x : a * v.x;
    v.y = v.y > 0.f ? v.y : a * v.y;
    v.z = v.z > 0.f ? v.z : a * v.z;
    v.w = v.w > 0.f ? v.w : a * v.w;
    float ss = fmaf(v.x, v.x, fmaf(v.y, v.y, fmaf(v.z, v.z, v.w * v.w)));
#pragma unroll
    for (int off = 32; off; off >>= 1) ss += __shfl_xor(ss, off, 64);
    const float inv = 1.0f / fmaxf(sqrtf(ss), 1e-12f);
    v.x *= inv; v.y *= inv; v.z *= inv; v.w *= inv;
    h4 oh, ol;
    oh[0] = (_Float16)v.x; ol[0] = (_Float16)(v.x - (float)oh[0]);
    oh[1] = (_Float16)v.y; ol[1] = (_Float16)(v.y - (float)oh[1]);
    oh[2] = (_Float16)v.z; ol[2] = (_Float16)(v.z - (float)oh[2]);
    oh[3] = (_Float16)v.w; ol[3] = (_Float16)(v.w - (float)oh[3]);
    const size_t o = (size_t)node * DD + lane * 4;
    *(h4*)(Hhi + o) = oh;
    *(h4*)(Hlo + o) = ol;
}

// ---------------- fp32 tiled GEMM for small fc tail -------------------------
// MODE 2: C = relu(AB + bias)
template <int MODE>
__global__ __launch_bounds__(256) void gemm128x64(const float* __restrict__ A,
                                                  const float* __restrict__ B,
                                                  float* __restrict__ C,
                                                  const float* __restrict__ bias,
                                                  int M, int N, int K) {
    __shared__ float As[16 * 132];
    __shared__ float Bs[16 * 68];
    const int t  = threadIdx.x;
    const int tx = t & 15;
    const int ty = t >> 4;
    const int m0 = blockIdx.x * 128;
    const int n0 = blockIdx.y * 64;
    const int arow = t >> 2;
    const int ak   = (t & 3) * 4;
    const int bk   = t >> 4;
    const int bc   = (t & 15) * 4;

    float acc[8][4];
#pragma unroll
    for (int i = 0; i < 8; ++i)
#pragma unroll
        for (int j = 0; j < 4; ++j) acc[i][j] = 0.f;

    for (int k0 = 0; k0 < K; k0 += 16) {
        float4 a0 = {0.f, 0.f, 0.f, 0.f}, a1 = {0.f, 0.f, 0.f, 0.f};
        const int r0 = m0 + arow, r1 = r0 + 64;
        if (r0 < M) a0 = *reinterpret_cast<const float4*>(A + (size_t)r0 * K + k0 + ak);
        if (r1 < M) a1 = *reinterpret_cast<const float4*>(A + (size_t)r1 * K + k0 + ak);
        const float4 bb = *reinterpret_cast<const float4*>(B + (size_t)(k0 + bk) * N + n0 + bc);
        __syncthreads();
        As[(ak + 0) * 132 + arow] = a0.x;
        As[(ak + 1) * 132 + arow] = a0.y;
        As[(ak + 2) * 132 + arow] = a0.z;
        As[(ak + 3) * 132 + arow] = a0.w;
        As[(ak + 0) * 132 + arow + 64] = a1.x;
        As[(ak + 1) * 132 + arow + 64] = a1.y;
        As[(ak + 2) * 132 + arow + 64] = a1.z;
        As[(ak + 3) * 132 + arow + 64] = a1.w;
        *reinterpret_cast<float4*>(&Bs[bk * 68 + bc]) = bb;
        __syncthreads();
#pragma unroll
        for (int k = 0; k < 16; ++k) {
            const float4 fa0 = *reinterpret_cast<const float4*>(&As[k * 132 + ty * 8]);
            const float4 fa1 = *reinterpret_cast<const float4*>(&As[k * 132 + ty * 8 + 4]);
            const float4 fb  = *reinterpret_cast<const float4*>(&Bs[k * 68 + tx * 4]);
            const float av[8] = {fa0.x, fa0.y, fa0.z, fa0.w, fa1.x, fa1.y, fa1.z, fa1.w};
            const float bv[4] = {fb.x, fb.y, fb.z, fb.w};
#pragma unroll
            for (int i = 0; i < 8; ++i)
#pragma unroll
                for (int j = 0; j < 4; ++j) acc[i][j] = fmaf(av[i], bv[j], acc[i][j]);
        }
    }
    const int row = m0 + ty * 8;
    const int col = n0 + tx * 4;
    const float4 bv = *reinterpret_cast<const float4*>(bias + col);
#pragma unroll
    for (int i = 0; i < 8; ++i) {
        const int m = row + i;
        if (m >= M) continue;
        float4 v = {acc[i][0], acc[i][1], acc[i][2], acc[i][3]};
        v.x = fmaxf(v.x + bv.x, 0.f); v.y = fmaxf(v.y + bv.y, 0.f);
        v.z = fmaxf(v.z + bv.z, 0.f); v.w = fmaxf(v.w + bv.w, 0.f);
        *reinterpret_cast<float4*>(C + (size_t)m * N + col) = v;
    }
}

// ---------------- pooled[batch[n]] += g[n]  (batch sorted) ------------------
__global__ __launch_bounds__(64) void pool_kernel(const float* __restrict__ g,
                                                  const int* __restrict__ batch,
                                                  float* __restrict__ pooled) {
    const int c     = threadIdx.x;
    const int start = blockIdx.x * 128;
    const int end   = min(start + 128, N_NODES);
    int cur = batch[start];
    float4 acc = {0.f, 0.f, 0.f, 0.f};
    for (int n = start; n < end; ++n) {
        const int bn = batch[n];
        if (bn != cur) {
            float* p = pooled + (size_t)cur * DD + c * 4;
            atomAddF(p + 0, acc.x); atomAddF(p + 1, acc.y);
            atomAddF(p + 2, acc.z); atomAddF(p + 3, acc.w);
            acc = {0.f, 0.f, 0.f, 0.f};
            cur = bn;
        }
        const float4 v = reinterpret_cast<const float4*>(g + (size_t)n * DD)[c];
        acc.x += v.x; acc.y += v.y; acc.z += v.z; acc.w += v.w;
    }
    float* p = pooled + (size_t)cur * DD + c * 4;
    atomAddF(p + 0, acc.x); atomAddF(p + 1, acc.y);
    atomAddF(p + 2, acc.z); atomAddF(p + 3, acc.w);
}

__global__ __launch_bounds__(64) void out_kernel(const float* __restrict__ z2,
                                                 const float* __restrict__ W,
                                                 const float* __restrict__ b,
                                                 float* __restrict__ out) {
    const int g = blockIdx.x;
    const int t = threadIdx.x;
    float s = 0.f;
#pragma unroll
    for (int j = 0; j < 8; ++j) s = fmaf(z2[(size_t)g * 512 + t + 64 * j], W[t + 64 * j], s);
#pragma unroll
    for (int off = 32; off; off >>= 1) s += __shfl_xor(s, off, 64);
    if (t == 0) {
        const float v = s + b[0];
        out[g] = v > 0.f ? v : 0.f;
    }
}

extern "C" void kernel_launch(void* const* d_in, const int* in_sizes, int n_in,
                              void* d_out, int out_size, void* d_ws, size_t ws_size,
                              hipStream_t stream) {
    const float* x       = (const float*)d_in[0];
    const int*   eidx    = (const int*)d_in[1];
    const int*   etype   = (const int*)d_in[2];
    const int*   batch   = (const int*)d_in[3];
    const float* enc_W   = (const float*)d_in[4];
    const float* enc_b   = (const float*)d_in[5];
    const float* prelu_a = (const float*)d_in[6];
    const float* rel_W   = (const float*)d_in[7];
    const float* root_W  = (const float*)d_in[8];
    const float* conv_b  = (const float*)d_in[9];
    const float* gp_W1   = (const float*)d_in[10];
    const float* gp_b1   = (const float*)d_in[11];
    const float* gp_W2   = (const float*)d_in[12];
    const float* gp_b2   = (const float*)d_in[13];
    const float* fc_W1   = (const float*)d_in[14];
    const float* fc_b1   = (const float*)d_in[15];
    const float* fc_W2   = (const float*)d_in[16];
    const float* fc_b2   = (const float*)d_in[17];
    const float* out_W   = (const float*)d_in[18];
    const float* out_b   = (const float*)d_in[19];
    float* out = (float*)d_out;

    uint8_t* wp = (uint8_t*)d_ws;
    auto alloc = [&](size_t bytes) {
        void* r = (void*)wp;
        wp += (bytes + 255) & ~(size_t)255;
        return r;
    };
    float*    base   = (float*)alloc((size_t)N_NODES * DD * 4);
    _Float16* Hhi    = (_Float16*)alloc((size_t)N_NODES * DD * 2);
    _Float16* Hlo    = (_Float16*)alloc((size_t)N_NODES * DD * 2);
    _Float16* agghi  = (_Float16*)alloc((size_t)2 * N_NODES * DD * 2);
    _Float16* agglo  = (_Float16*)alloc((size_t)2 * N_NODES * DD * 2);
    _Float16* wthi   = (_Float16*)alloc((size_t)N_LAYERS * 256 * 1792 * 2);
    _Float16* wtlo   = (_Float16*)alloc((size_t)N_LAYERS * 256 * 1792 * 2);
    _Float16* wtg1hi = (_Float16*)alloc((size_t)256 * 256 * 2);
    _Float16* wtg1lo = (_Float16*)alloc((size_t)256 * 256 * 2);
    _Float16* wtg2hi = (_Float16*)alloc((size_t)256 * 256 * 2);
    _Float16* wtg2lo = (_Float16*)alloc((size_t)256 * 256 * 2);
    float*    pooled = (float*)alloc((size_t)NUM_GRAPHS * DD * 4);
    float*    z1     = (float*)alloc((size_t)NUM_GRAPHS * 1024 * 4);
    float*    z2     = (float*)alloc((size_t)NUM_GRAPHS * 512 * 4);
    int*      ioff   = (int*)alloc((size_t)(NKEYS + 1) * 4);
    int*      icur   = (int*)alloc((size_t)NKEYS * 4);
    int*      ibsum  = (int*)alloc(256 * 4);
    int*      isrc   = (int*)alloc((size_t)N_EDGES * 4);

    const int* src = eidx;
    const int* dst = eidx + N_EDGES;

    // ---- weight prep (every call; ws is re-poisoned) ----
    const size_t wtot = (size_t)N_LAYERS * 7 * 256 * 256;
    wsplit_rel_kernel<<<(int)((wtot + 255) / 256), 256, 0, stream>>>(rel_W, root_W, wthi, wtlo);
    wsplit_tr_kernel<<<256, 256, 0, stream>>>(gp_W1, wtg1hi, wtg1lo);
    wsplit_tr_kernel<<<256, 256, 0, stream>>>(gp_W2, wtg2hi, wtg2lo);

    // ---- CSR build ----
    hipMemsetAsync(icur, 0, (size_t)NKEYS * sizeof(int), stream);
    const int eb = (N_EDGES + 255) / 256;
    hist_kernel<<<eb, 256, 0, stream>>>(dst, etype, icur);
    scan1_kernel<<<SCAN_NB, SCAN_T, 0, stream>>>(icur, ioff, ibsum);
    scan2_kernel<<<1, SCAN_T, 0, stream>>>(ibsum, SCAN_NB);
    scan3_kernel<<<SCAN_NB, SCAN_T, 0, stream>>>(ioff, ibsum);
    hipMemcpyAsync(icur, ioff, (size_t)NKEYS * sizeof(int), hipMemcpyDeviceToDevice, stream);
    csr_fill_kernel<<<eb, 256, 0, stream>>>(src, dst, etype, icur, isrc);

    // ---- encoder ----
    enc_kernel<<<N_NODES, 256, 0, stream>>>(x, enc_W, enc_b, Hhi, Hlo);

    const dim3 gM((N_NODES + 127) / 128, 2);
    const int  nodeb = (N_NODES + 3) / 4;

    for (int L = 0; L < N_LAYERS; ++L) {
        const _Float16* Bh = wthi + (size_t)L * 256 * 1792;
        const _Float16* Bl = wtlo + (size_t)L * 256 * 1792;
        // chunk 0: rels 0,1 + root + bias + skip  (K = 512 agg + 256 h)
        agg2_kernel<<<nodeb, 256, 0, stream>>>(Hhi, Hlo, ioff, isrc, agghi, agglo, 0);
        mfma_gemm<0><<<gM, 256, 0, stream>>>(agghi, agglo, Hhi, Hlo, Bh, Bl,
                                             1792, 0, 1536, 512, 768,
                                             base, nullptr, nullptr, conv_b + L * DD, N_NODES);
        // chunk 1: rels 2,3 accumulate
        agg2_kernel<<<nodeb, 256, 0, stream>>>(Hhi, Hlo, ioff, isrc, agghi, agglo, 2);
        mfma_gemm<1><<<gM, 256, 0, stream>>>(agghi, agglo, Hhi, Hlo, Bh, Bl,
                                             1792, 512, 0, 512, 512,
                                             base, nullptr, nullptr, nullptr, N_NODES);
        // chunk 2: rels 4,5 accumulate
        agg2_kernel<<<nodeb, 256, 0, stream>>>(Hhi, Hlo, ioff, isrc, agghi, agglo, 4);
        mfma_gemm<1><<<gM, 256, 0, stream>>>(agghi, agglo, Hhi, Hlo, Bh, Bl,
                                             1792, 1024, 0, 512, 512,
                                             base, nullptr, nullptr, nullptr, N_NODES);
        finalize_kernel<<<nodeb, 256, 0, stream>>>(base, Hhi, Hlo, prelu_a);
    }

    // gp1 = relu(h @ gp_W1 + gp_b1) -> planes (reuse agg buffers)
    mfma_gemm<2><<<gM, 256, 0, stream>>>(nullptr, nullptr, Hhi, Hlo, wtg1hi, wtg1lo,
                                         256, 0, 0, 0, 256,
                                         nullptr, agghi, agglo, gp_b1, N_NODES);
    // gp2 = gp1 @ gp_W2 + gp_b2 -> base (fp32)
    mfma_gemm<3><<<gM, 256, 0, stream>>>(nullptr, nullptr, agghi, agglo, wtg2hi, wtg2lo,
                                         256, 0, 0, 0, 256,
                                         base, nullptr, nullptr, gp_b2, N_NODES);

    hipMemsetAsync(pooled, 0, (size_t)NUM_GRAPHS * DD * sizeof(float), stream);
    pool_kernel<<<(N_NODES + 127) / 128, 64, 0, stream>>>(base, batch, pooled);

    gemm128x64<2><<<dim3(4, 16), 256, 0, stream>>>(pooled, fc_W1, z1, fc_b1,
                                                   NUM_GRAPHS, 1024, DD);
    gemm128x64<2><<<dim3(4, 8), 256, 0, stream>>>(z1, fc_W2, z2, fc_b2,
                                                  NUM_GRAPHS, 512, 1024);
    out_kernel<<<NUM_GRAPHS, 64, 0, stream>>>(z2, out_W, out_b, out);
}